// Round 1
// 747.144 us; speedup vs baseline: 1.1526x; 1.1526x over previous
//
#include <hip/hip_runtime.h>

#define RES   512
#define NCH   64            // channels
#define SP    (RES * RES)   // 262144 texels per plane

// Morton binning for point sort (3D locality => locality in all 3 plane projections)
#define NBITS 5
#define NSIDE (1 << NBITS)           // 32 voxels per axis
#define NBINS (1 << (3 * NBITS))     // 32768 bins, ~32 pts/bin at 1M pts

// ---------------------------------------------------------------------------
// Kernel 1: transpose planes (3, C, R, R) -> (3, R*R, C)  [texel-major]
// Tile 64ch x 128sp: per-channel global reads are 512 B contiguous with all 8
// float4 loads in flight (vs 256 B before: theory = tiny strided streams were
// DRAM-hostile). Writes are 1 KB contiguous per wave instruction.
// LDS 64 x 129 floats (33 KB) -> 4 blocks/CU, 16 waves. 2-way bank alias max.
// grid = 3 * (SP/128) = 6144 blocks, 256 threads.
// ---------------------------------------------------------------------------
__global__ __launch_bounds__(256) void transpose_planes(
    const float* __restrict__ in, float* __restrict__ out)
{
    __shared__ float tile[64][129];   // 129: column reads land on 32 distinct banks (2-way)

    int b     = blockIdx.x;
    int plane = b >> 11;              // 2048 tiles per plane
    int s0    = (b & 2047) << 7;      // * 128 spatial base
    const float* src = in  + (size_t)plane * NCH * SP;
    float*       dst = out + (size_t)plane * SP  * NCH;

    int tid = threadIdx.x;
    int r   = tid >> 4;               // 0..15
    int c4  = (tid & 15) << 2;        // 0,4,...,60

    // load: row = channel, col = spatial. Issue all 8 loads before LDS writes.
    float4 vv[8];
    #pragma unroll
    for (int it = 0; it < 8; ++it) {
        int ch = r + (it & 3) * 16;            // 0..63
        int sp = ((it >> 2) << 6) + c4;        // 0..124
        vv[it] = *(const float4*)(src + (size_t)ch * SP + s0 + sp);
    }
    #pragma unroll
    for (int it = 0; it < 8; ++it) {
        int ch = r + (it & 3) * 16;
        int sp = ((it >> 2) << 6) + c4;
        tile[ch][sp + 0] = vv[it].x;
        tile[ch][sp + 1] = vv[it].y;
        tile[ch][sp + 2] = vv[it].z;
        tile[ch][sp + 3] = vv[it].w;
    }
    __syncthreads();
    // store: row = spatial, col = channel (coalesced float4 along channel)
    #pragma unroll
    for (int it = 0; it < 8; ++it) {
        int s = r + (it & 3) * 16 + ((it >> 2) << 6);   // 0..127
        float4 v;
        v.x = tile[c4 + 0][s];
        v.y = tile[c4 + 1][s];
        v.z = tile[c4 + 2][s];
        v.w = tile[c4 + 3][s];
        *(float4*)(dst + (size_t)(s0 + s) * NCH + c4) = v;
    }
}

// ---------------------------------------------------------------------------
// Morton helpers
// ---------------------------------------------------------------------------
__device__ __forceinline__ unsigned part1by2(unsigned v)
{
    v &= 0x3FF;
    v = (v | (v << 16)) & 0x030000FF;
    v = (v | (v <<  8)) & 0x0300F00F;
    v = (v | (v <<  4)) & 0x030C30C3;
    v = (v | (v <<  2)) & 0x09249249;
    return v;
}

__device__ __forceinline__ unsigned bin_of(float x, float y, float z)
{
    int ix = (int)((x + 1.0f) * 0.5f * (float)NSIDE);
    int iy = (int)((y + 1.0f) * 0.5f * (float)NSIDE);
    int iz = (int)((z + 1.0f) * 0.5f * (float)NSIDE);
    ix = min(max(ix, 0), NSIDE - 1);
    iy = min(max(iy, 0), NSIDE - 1);
    iz = min(max(iz, 0), NSIDE - 1);
    return part1by2((unsigned)ix) | (part1by2((unsigned)iy) << 1)
         | (part1by2((unsigned)iz) << 2);
}

// Kernel S1: histogram of Morton bins
__global__ __launch_bounds__(256) void hist_kernel(
    const float* __restrict__ pts, unsigned* __restrict__ hist, int npts)
{
    int i = blockIdx.x * 256 + threadIdx.x;
    if (i >= npts) return;
    float x = pts[3 * (size_t)i + 0];
    float y = pts[3 * (size_t)i + 1];
    float z = pts[3 * (size_t)i + 2];
    atomicAdd(&hist[bin_of(x, y, z)], 1u);
}

// Kernel S2: exclusive prefix sum over 32768 bins (single block, 1024 thr)
__global__ __launch_bounds__(1024) void scan_kernel(
    const unsigned* __restrict__ hist, unsigned* __restrict__ offs)
{
    __shared__ unsigned partial[1024];
    int t = threadIdx.x;
    unsigned base = (unsigned)t * 32;
    unsigned local[32];
    unsigned s = 0;
    #pragma unroll
    for (int k = 0; k < 32; ++k) { local[k] = s; s += hist[base + k]; }
    partial[t] = s;
    __syncthreads();
    for (int d = 1; d < 1024; d <<= 1) {
        unsigned v = (t >= d) ? partial[t - d] : 0u;
        __syncthreads();
        partial[t] += v;
        __syncthreads();
    }
    unsigned chunk_excl = (t == 0) ? 0u : partial[t - 1];
    #pragma unroll
    for (int k = 0; k < 32; ++k) offs[base + k] = chunk_excl + local[k];
}

// Kernel S3: scatter point index + coords into Morton-sorted order
__global__ __launch_bounds__(256) void scatter_kernel(
    const float* __restrict__ pts, unsigned* __restrict__ offs,
    unsigned* __restrict__ perm, float* __restrict__ spts, int npts)
{
    int i = blockIdx.x * 256 + threadIdx.x;
    if (i >= npts) return;
    float x = pts[3 * (size_t)i + 0];
    float y = pts[3 * (size_t)i + 1];
    float z = pts[3 * (size_t)i + 2];
    unsigned pos = atomicAdd(&offs[bin_of(x, y, z)], 1u);
    perm[pos] = (unsigned)i;
    spts[3 * (size_t)pos + 0] = x;
    spts[3 * (size_t)pos + 1] = y;
    spts[3 * (size_t)pos + 2] = z;
}

// ---------------------------------------------------------------------------
// Kernel 2 (sorted): gather from texel-major planes in Morton order.
// 16 threads per point, float4 of channels each; texel access = 256 B/16 lanes.
// Morton order => consecutive waves probe neighboring texels => L2 hits.
// Chunked XCD swizzle: each XCD's L2 sees a contiguous Morton span.
// ---------------------------------------------------------------------------
__global__ __launch_bounds__(256) void gather_sorted(
    const float* __restrict__ spts, const unsigned* __restrict__ perm,
    const float* __restrict__ tp, float* __restrict__ out,
    int npts, int nblk)
{
    int cpx = nblk >> 3;                       // nblk % 8 == 0 guaranteed by launch
    int b   = blockIdx.x;
    int swz = (b & 7) * cpx + (b >> 3);        // bijective chunked XCD swizzle
    int t   = swz * 256 + threadIdx.x;
    int j   = t >> 4;                          // sorted position
    if (j >= npts) return;
    int cg  = (t & 15) << 2;                   // channel offset 0..60

    float px = spts[3 * (size_t)j + 0];
    float py = spts[3 * (size_t)j + 1];
    float pz = spts[3 * (size_t)j + 2];

    float us[3] = {px, px, py};
    float vs[3] = {py, pz, pz};

    float4 acc = make_float4(0.f, 0.f, 0.f, 0.f);

    #pragma unroll
    for (int pl = 0; pl < 3; ++pl) {
        float fx = fminf(fmaxf((us[pl] + 1.0f) * 0.5f * 511.0f, 0.0f), 511.0f);
        float fy = fminf(fmaxf((vs[pl] + 1.0f) * 0.5f * 511.0f, 0.0f), 511.0f);
        float x0f = floorf(fx), y0f = floorf(fy);
        int   x0  = (int)x0f,  y0  = (int)y0f;
        float wx  = fx - x0f,  wy  = fy - y0f;
        int   x1  = min(x0 + 1, RES - 1);
        int   y1  = min(y0 + 1, RES - 1);

        const float* base = tp + (size_t)pl * SP * NCH;
        float4 v00 = *(const float4*)(base + ((size_t)(y0 * RES + x0) * NCH) + cg);
        float4 v01 = *(const float4*)(base + ((size_t)(y0 * RES + x1) * NCH) + cg);
        float4 v10 = *(const float4*)(base + ((size_t)(y1 * RES + x0) * NCH) + cg);
        float4 v11 = *(const float4*)(base + ((size_t)(y1 * RES + x1) * NCH) + cg);

        float w00 = (1.0f - wx) * (1.0f - wy);
        float w01 = wx * (1.0f - wy);
        float w10 = (1.0f - wx) * wy;
        float w11 = wx * wy;

        acc.x += w00 * v00.x + w01 * v01.x + w10 * v10.x + w11 * v11.x;
        acc.y += w00 * v00.y + w01 * v01.y + w10 * v10.y + w11 * v11.y;
        acc.z += w00 * v00.z + w01 * v01.z + w10 * v10.z + w11 * v11.z;
        acc.w += w00 * v00.w + w01 * v01.w + w10 * v10.w + w11 * v11.w;
    }

    unsigned i = perm[j];                      // broadcast within 16-lane group
    *(float4*)(out + (size_t)i * NCH + cg) = acc;
}

// ---------------------------------------------------------------------------
// Fallback tier: unsorted gather from texel-major planes (previous best).
// ---------------------------------------------------------------------------
__global__ __launch_bounds__(256) void gather_tp(
    const float* __restrict__ pts,
    const float* __restrict__ tp,
    float* __restrict__ out, int npts)
{
    int t  = blockIdx.x * 256 + threadIdx.x;
    int pt = t >> 4;
    if (pt >= npts) return;
    int cg = (t & 15) << 2;

    float px = pts[3 * (size_t)pt + 0];
    float py = pts[3 * (size_t)pt + 1];
    float pz = pts[3 * (size_t)pt + 2];

    float us[3] = {px, px, py};
    float vs[3] = {py, pz, pz};

    float4 acc = make_float4(0.f, 0.f, 0.f, 0.f);

    #pragma unroll
    for (int pl = 0; pl < 3; ++pl) {
        float fx = fminf(fmaxf((us[pl] + 1.0f) * 0.5f * 511.0f, 0.0f), 511.0f);
        float fy = fminf(fmaxf((vs[pl] + 1.0f) * 0.5f * 511.0f, 0.0f), 511.0f);
        float x0f = floorf(fx), y0f = floorf(fy);
        int   x0  = (int)x0f,  y0  = (int)y0f;
        float wx  = fx - x0f,  wy  = fy - y0f;
        int   x1  = min(x0 + 1, RES - 1);
        int   y1  = min(y0 + 1, RES - 1);

        const float* base = tp + (size_t)pl * SP * NCH;
        float4 v00 = *(const float4*)(base + ((size_t)(y0 * RES + x0) * NCH) + cg);
        float4 v01 = *(const float4*)(base + ((size_t)(y0 * RES + x1) * NCH) + cg);
        float4 v10 = *(const float4*)(base + ((size_t)(y1 * RES + x0) * NCH) + cg);
        float4 v11 = *(const float4*)(base + ((size_t)(y1 * RES + x1) * NCH) + cg);

        float w00 = (1.0f - wx) * (1.0f - wy);
        float w01 = wx * (1.0f - wy);
        float w10 = (1.0f - wx) * wy;
        float w11 = wx * wy;

        acc.x += w00 * v00.x + w01 * v01.x + w10 * v10.x + w11 * v11.x;
        acc.y += w00 * v00.y + w01 * v01.y + w10 * v10.y + w11 * v11.y;
        acc.z += w00 * v00.z + w01 * v01.z + w10 * v10.z + w11 * v11.z;
        acc.w += w00 * v00.w + w01 * v01.w + w10 * v10.w + w11 * v11.w;
    }

    *(float4*)(out + (size_t)pt * NCH + cg) = acc;
}

// ---------------------------------------------------------------------------
// Last-resort fallback: direct gather from original (3, C, R, R) layout.
// ---------------------------------------------------------------------------
__global__ __launch_bounds__(256) void gather_direct(
    const float* __restrict__ pts,
    const float* __restrict__ planes,
    float* __restrict__ out, int npts)
{
    long t = (long)blockIdx.x * 256 + threadIdx.x;
    int pt = (int)(t >> 6);
    if (pt >= npts) return;
    int ch = (int)(t & 63);

    float px = pts[3 * (size_t)pt + 0];
    float py = pts[3 * (size_t)pt + 1];
    float pz = pts[3 * (size_t)pt + 2];
    float us[3] = {px, px, py};
    float vs[3] = {py, pz, pz};

    float acc = 0.0f;
    #pragma unroll
    for (int pl = 0; pl < 3; ++pl) {
        float fx = fminf(fmaxf((us[pl] + 1.0f) * 0.5f * 511.0f, 0.0f), 511.0f);
        float fy = fminf(fmaxf((vs[pl] + 1.0f) * 0.5f * 511.0f, 0.0f), 511.0f);
        float x0f = floorf(fx), y0f = floorf(fy);
        int   x0  = (int)x0f,  y0  = (int)y0f;
        float wx  = fx - x0f,  wy  = fy - y0f;
        int   x1  = min(x0 + 1, RES - 1);
        int   y1  = min(y0 + 1, RES - 1);

        const float* base = planes + (size_t)pl * NCH * SP + (size_t)ch * SP;
        float v00 = base[y0 * RES + x0];
        float v01 = base[y0 * RES + x1];
        float v10 = base[y1 * RES + x0];
        float v11 = base[y1 * RES + x1];

        acc += v00 * ((1.0f - wx) * (1.0f - wy))
             + v01 * (wx * (1.0f - wy))
             + v10 * ((1.0f - wx) * wy)
             + v11 * (wx * wy);
    }
    out[(size_t)pt * NCH + ch] = acc;
}

extern "C" void kernel_launch(void* const* d_in, const int* in_sizes, int n_in,
                              void* d_out, int out_size, void* d_ws, size_t ws_size,
                              hipStream_t stream)
{
    (void)n_in; (void)out_size;
    const float* pts    = (const float*)d_in[0];
    const float* planes = (const float*)d_in[1];
    float*       out    = (float*)d_out;
    int npts = in_sizes[0] / 3;

    // workspace layout
    size_t sz_tp     = (size_t)3 * NCH * SP * sizeof(float);       // 201.3 MB
    size_t off_spts  = sz_tp;
    size_t sz_spts   = (size_t)npts * 3 * sizeof(float);
    size_t off_perm  = off_spts + sz_spts;
    size_t sz_perm   = (size_t)npts * sizeof(unsigned);
    size_t off_hist  = off_perm + sz_perm;
    size_t off_offs  = off_hist + (size_t)NBINS * sizeof(unsigned);
    size_t need_sort = off_offs + (size_t)NBINS * sizeof(unsigned);

    int nptblk = (npts + 255) / 256;

    if (ws_size >= need_sort) {
        float*    tp   = (float*)d_ws;
        float*    spts = (float*)((char*)d_ws + off_spts);
        unsigned* perm = (unsigned*)((char*)d_ws + off_perm);
        unsigned* hist = (unsigned*)((char*)d_ws + off_hist);
        unsigned* offs = (unsigned*)((char*)d_ws + off_offs);

        transpose_planes<<<3 * (SP / 128), 256, 0, stream>>>(planes, tp);

        hipMemsetAsync(hist, 0, (size_t)NBINS * sizeof(unsigned), stream);
        hist_kernel<<<nptblk, 256, 0, stream>>>(pts, hist, npts);
        scan_kernel<<<1, 1024, 0, stream>>>(hist, offs);
        scatter_kernel<<<nptblk, 256, 0, stream>>>(pts, offs, perm, spts, npts);

        long nthr = (long)npts * 16;
        int  nblk = (int)((nthr + 255) / 256);
        nblk = (nblk + 7) & ~7;                 // multiple of 8 for bijective swizzle
        gather_sorted<<<nblk, 256, 0, stream>>>(spts, perm, tp, out, npts, nblk);
    } else if (ws_size >= sz_tp) {
        transpose_planes<<<3 * (SP / 128), 256, 0, stream>>>(planes, (float*)d_ws);
        long nthr = (long)npts * 16;
        gather_tp<<<(int)((nthr + 255) / 256), 256, 0, stream>>>(
            pts, (const float*)d_ws, out, npts);
    } else {
        long nthr = (long)npts * 64;
        gather_direct<<<(int)((nthr + 255) / 256), 256, 0, stream>>>(
            pts, planes, out, npts);
    }
}

// Round 2
// 665.504 us; speedup vs baseline: 1.2940x; 1.1227x over previous
//
#include <hip/hip_runtime.h>

#define RES   512
#define NCH   64            // channels
#define SP    (RES * RES)   // 262144 texels per plane

// Morton binning for point sort (3D locality => locality in all 3 plane projections)
#define NBITS 5
#define NSIDE (1 << NBITS)           // 32 voxels per axis
#define NBINS (1 << (3 * NBITS))     // 32768 bins, ~32 pts/bin at 1M pts

#define TRBLK 6144                   // transpose blocks: 3 * (SP/128)

typedef float v4f __attribute__((ext_vector_type(4)));

__device__ __forceinline__ v4f nt_load4(const float* p)
{
    return __builtin_nontemporal_load((const v4f*)p);
}
__device__ __forceinline__ void nt_store4(float* p, v4f v)
{
    __builtin_nontemporal_store(v, (v4f*)p);
}

// ---------------------------------------------------------------------------
// Morton helpers
// ---------------------------------------------------------------------------
__device__ __forceinline__ unsigned part1by2(unsigned v)
{
    v &= 0x3FF;
    v = (v | (v << 16)) & 0x030000FF;
    v = (v | (v <<  8)) & 0x0300F00F;
    v = (v | (v <<  4)) & 0x030C30C3;
    v = (v | (v <<  2)) & 0x09249249;
    return v;
}

__device__ __forceinline__ unsigned bin_of(float x, float y, float z)
{
    int ix = (int)((x + 1.0f) * 0.5f * (float)NSIDE);
    int iy = (int)((y + 1.0f) * 0.5f * (float)NSIDE);
    int iz = (int)((z + 1.0f) * 0.5f * (float)NSIDE);
    ix = min(max(ix, 0), NSIDE - 1);
    iy = min(max(iy, 0), NSIDE - 1);
    iz = min(max(iz, 0), NSIDE - 1);
    return part1by2((unsigned)ix) | (part1by2((unsigned)iy) << 1)
         | (part1by2((unsigned)iz) << 2);
}

// ---------------------------------------------------------------------------
// Kernel 1 (fused): blocks [0, TRBLK) transpose planes (3,C,R,R)->(3,R*R,C);
// blocks [TRBLK, ...) compute the Morton-bin histogram (hidden under transpose).
// Transpose reads use nt-loads (one-shot stream, don't thrash L2/L3);
// tp writes stay cached: the whole 201 MB tp fits L3 and the gather wants it there.
// ---------------------------------------------------------------------------
__global__ __launch_bounds__(256) void transpose_hist(
    const float* __restrict__ in, float* __restrict__ out,
    const float* __restrict__ pts, unsigned* __restrict__ hist, int npts)
{
    __shared__ float tile[64][129];   // 129: 2-way bank alias max on column reads

    int b = blockIdx.x;
    if (b >= TRBLK) {
        int i = (b - TRBLK) * 256 + threadIdx.x;
        if (i < npts) {
            float x = pts[3 * (size_t)i + 0];
            float y = pts[3 * (size_t)i + 1];
            float z = pts[3 * (size_t)i + 2];
            atomicAdd(&hist[bin_of(x, y, z)], 1u);
        }
        return;
    }

    int plane = b >> 11;              // 2048 tiles per plane
    int s0    = (b & 2047) << 7;      // * 128 spatial base
    const float* src = in  + (size_t)plane * NCH * SP;
    float*       dst = out + (size_t)plane * SP  * NCH;

    int tid = threadIdx.x;
    int r   = tid >> 4;               // 0..15
    int c4  = (tid & 15) << 2;        // 0,4,...,60

    v4f vv[8];
    #pragma unroll
    for (int it = 0; it < 8; ++it) {
        int ch = r + (it & 3) * 16;            // 0..63
        int sp = ((it >> 2) << 6) + c4;        // 0..124
        vv[it] = nt_load4(src + (size_t)ch * SP + s0 + sp);
    }
    #pragma unroll
    for (int it = 0; it < 8; ++it) {
        int ch = r + (it & 3) * 16;
        int sp = ((it >> 2) << 6) + c4;
        tile[ch][sp + 0] = vv[it][0];
        tile[ch][sp + 1] = vv[it][1];
        tile[ch][sp + 2] = vv[it][2];
        tile[ch][sp + 3] = vv[it][3];
    }
    __syncthreads();
    #pragma unroll
    for (int it = 0; it < 8; ++it) {
        int s = r + (it & 3) * 16 + ((it >> 2) << 6);   // 0..127
        v4f v;
        v[0] = tile[c4 + 0][s];
        v[1] = tile[c4 + 1][s];
        v[2] = tile[c4 + 2][s];
        v[3] = tile[c4 + 3][s];
        *(v4f*)(dst + (size_t)(s0 + s) * NCH + c4) = v;   // cached: keep tp in L3
    }
}

// ---------------------------------------------------------------------------
// Kernel S2: exclusive prefix sum over 32768 bins (single block, 1024 thr)
// ---------------------------------------------------------------------------
__global__ __launch_bounds__(1024) void scan_kernel(
    const unsigned* __restrict__ hist, unsigned* __restrict__ offs)
{
    __shared__ unsigned partial[1024];
    int t = threadIdx.x;
    unsigned base = (unsigned)t * 32;
    unsigned local[32];
    unsigned s = 0;
    #pragma unroll
    for (int k = 0; k < 32; ++k) { local[k] = s; s += hist[base + k]; }
    partial[t] = s;
    __syncthreads();
    for (int d = 1; d < 1024; d <<= 1) {
        unsigned v = (t >= d) ? partial[t - d] : 0u;
        __syncthreads();
        partial[t] += v;
        __syncthreads();
    }
    unsigned chunk_excl = (t == 0) ? 0u : partial[t - 1];
    #pragma unroll
    for (int k = 0; k < 32; ++k) offs[base + k] = chunk_excl + local[k];
}

// ---------------------------------------------------------------------------
// Kernel S3: scatter (x,y,z,bits(idx)) as ONE aligned float4 per point into
// Morton-sorted order. No separate perm array; 16 B aligned scattered writes.
// ---------------------------------------------------------------------------
__global__ __launch_bounds__(256) void scatter_kernel(
    const float* __restrict__ pts, unsigned* __restrict__ offs,
    float* __restrict__ spts4, int npts)
{
    int i = blockIdx.x * 256 + threadIdx.x;
    if (i >= npts) return;
    float x = pts[3 * (size_t)i + 0];
    float y = pts[3 * (size_t)i + 1];
    float z = pts[3 * (size_t)i + 2];
    unsigned pos = atomicAdd(&offs[bin_of(x, y, z)], 1u);
    v4f v;
    v[0] = x; v[1] = y; v[2] = z; v[3] = __uint_as_float((unsigned)i);
    *(v4f*)(spts4 + 4 * (size_t)pos) = v;
}

// ---------------------------------------------------------------------------
// Kernel 2 (sorted): gather from texel-major planes in Morton order.
// 16 threads per point, float4 of channels each; texel access = 256 B/16 lanes.
// NT stores for out: 262 MB of streaming writes must NOT evict the L3-resident
// 201 MB plane set (that eviction was the round-1 overfetch: FETCH 614 MB vs
// ~217 MB compulsory). Chunked bijective XCD swizzle for per-XCD L2 spans.
// ---------------------------------------------------------------------------
__global__ __launch_bounds__(256) void gather_sorted(
    const float* __restrict__ spts4,
    const float* __restrict__ tp, float* __restrict__ out,
    int npts, int nblk)
{
    int cpx = nblk >> 3;                       // nblk % 8 == 0 by launch
    int b   = blockIdx.x;
    int swz = (b & 7) * cpx + (b >> 3);        // bijective chunked XCD swizzle
    int t   = swz * 256 + threadIdx.x;
    int j   = t >> 4;                          // sorted position
    if (j >= npts) return;
    int cg  = (t & 15) << 2;                   // channel offset 0..60

    v4f s = *(const v4f*)(spts4 + 4 * (size_t)j);   // broadcast within group
    float px = s[0], py = s[1], pz = s[2];
    unsigned idx = __float_as_uint(s[3]);

    float us[3] = {px, px, py};
    float vs[3] = {py, pz, pz};

    v4f acc = {0.f, 0.f, 0.f, 0.f};

    #pragma unroll
    for (int pl = 0; pl < 3; ++pl) {
        float fx = fminf(fmaxf((us[pl] + 1.0f) * 0.5f * 511.0f, 0.0f), 511.0f);
        float fy = fminf(fmaxf((vs[pl] + 1.0f) * 0.5f * 511.0f, 0.0f), 511.0f);
        float x0f = floorf(fx), y0f = floorf(fy);
        int   x0  = (int)x0f,  y0  = (int)y0f;
        float wx  = fx - x0f,  wy  = fy - y0f;
        int   x1  = min(x0 + 1, RES - 1);
        int   y1  = min(y0 + 1, RES - 1);

        const float* base = tp + (size_t)pl * SP * NCH;
        v4f v00 = *(const v4f*)(base + ((size_t)(y0 * RES + x0) * NCH) + cg);
        v4f v01 = *(const v4f*)(base + ((size_t)(y0 * RES + x1) * NCH) + cg);
        v4f v10 = *(const v4f*)(base + ((size_t)(y1 * RES + x0) * NCH) + cg);
        v4f v11 = *(const v4f*)(base + ((size_t)(y1 * RES + x1) * NCH) + cg);

        float w00 = (1.0f - wx) * (1.0f - wy);
        float w01 = wx * (1.0f - wy);
        float w10 = (1.0f - wx) * wy;
        float w11 = wx * wy;

        acc += w00 * v00 + w01 * v01 + w10 * v10 + w11 * v11;
    }

    nt_store4(out + (size_t)idx * NCH + cg, acc);
}

// ---------------------------------------------------------------------------
// Fallback tier: unsorted gather from texel-major planes.
// ---------------------------------------------------------------------------
__global__ __launch_bounds__(256) void gather_tp(
    const float* __restrict__ pts,
    const float* __restrict__ tp,
    float* __restrict__ out, int npts)
{
    int t  = blockIdx.x * 256 + threadIdx.x;
    int pt = t >> 4;
    if (pt >= npts) return;
    int cg = (t & 15) << 2;

    float px = pts[3 * (size_t)pt + 0];
    float py = pts[3 * (size_t)pt + 1];
    float pz = pts[3 * (size_t)pt + 2];

    float us[3] = {px, px, py};
    float vs[3] = {py, pz, pz};

    v4f acc = {0.f, 0.f, 0.f, 0.f};

    #pragma unroll
    for (int pl = 0; pl < 3; ++pl) {
        float fx = fminf(fmaxf((us[pl] + 1.0f) * 0.5f * 511.0f, 0.0f), 511.0f);
        float fy = fminf(fmaxf((vs[pl] + 1.0f) * 0.5f * 511.0f, 0.0f), 511.0f);
        float x0f = floorf(fx), y0f = floorf(fy);
        int   x0  = (int)x0f,  y0  = (int)y0f;
        float wx  = fx - x0f,  wy  = fy - y0f;
        int   x1  = min(x0 + 1, RES - 1);
        int   y1  = min(y0 + 1, RES - 1);

        const float* base = tp + (size_t)pl * SP * NCH;
        v4f v00 = *(const v4f*)(base + ((size_t)(y0 * RES + x0) * NCH) + cg);
        v4f v01 = *(const v4f*)(base + ((size_t)(y0 * RES + x1) * NCH) + cg);
        v4f v10 = *(const v4f*)(base + ((size_t)(y1 * RES + x0) * NCH) + cg);
        v4f v11 = *(const v4f*)(base + ((size_t)(y1 * RES + x1) * NCH) + cg);

        float w00 = (1.0f - wx) * (1.0f - wy);
        float w01 = wx * (1.0f - wy);
        float w10 = (1.0f - wx) * wy;
        float w11 = wx * wy;

        acc += w00 * v00 + w01 * v01 + w10 * v10 + w11 * v11;
    }

    *(v4f*)(out + (size_t)pt * NCH + cg) = acc;
}

// ---------------------------------------------------------------------------
// Last-resort fallback: direct gather from original (3, C, R, R) layout.
// ---------------------------------------------------------------------------
__global__ __launch_bounds__(256) void gather_direct(
    const float* __restrict__ pts,
    const float* __restrict__ planes,
    float* __restrict__ out, int npts)
{
    long t = (long)blockIdx.x * 256 + threadIdx.x;
    int pt = (int)(t >> 6);
    if (pt >= npts) return;
    int ch = (int)(t & 63);

    float px = pts[3 * (size_t)pt + 0];
    float py = pts[3 * (size_t)pt + 1];
    float pz = pts[3 * (size_t)pt + 2];
    float us[3] = {px, px, py};
    float vs[3] = {py, pz, pz};

    float acc = 0.0f;
    #pragma unroll
    for (int pl = 0; pl < 3; ++pl) {
        float fx = fminf(fmaxf((us[pl] + 1.0f) * 0.5f * 511.0f, 0.0f), 511.0f);
        float fy = fminf(fmaxf((vs[pl] + 1.0f) * 0.5f * 511.0f, 0.0f), 511.0f);
        float x0f = floorf(fx), y0f = floorf(fy);
        int   x0  = (int)x0f,  y0  = (int)y0f;
        float wx  = fx - x0f,  wy  = fy - y0f;
        int   x1  = min(x0 + 1, RES - 1);
        int   y1  = min(y0 + 1, RES - 1);

        const float* base = planes + (size_t)pl * NCH * SP + (size_t)ch * SP;
        float v00 = base[y0 * RES + x0];
        float v01 = base[y0 * RES + x1];
        float v10 = base[y1 * RES + x0];
        float v11 = base[y1 * RES + x1];

        acc += v00 * ((1.0f - wx) * (1.0f - wy))
             + v01 * (wx * (1.0f - wy))
             + v10 * ((1.0f - wx) * wy)
             + v11 * (wx * wy);
    }
    out[(size_t)pt * NCH + ch] = acc;
}

extern "C" void kernel_launch(void* const* d_in, const int* in_sizes, int n_in,
                              void* d_out, int out_size, void* d_ws, size_t ws_size,
                              hipStream_t stream)
{
    (void)n_in; (void)out_size;
    const float* pts    = (const float*)d_in[0];
    const float* planes = (const float*)d_in[1];
    float*       out    = (float*)d_out;
    int npts = in_sizes[0] / 3;

    // workspace layout
    size_t sz_tp     = (size_t)3 * NCH * SP * sizeof(float);       // 201.3 MB
    size_t off_spts  = sz_tp;
    size_t sz_spts   = (size_t)npts * 4 * sizeof(float);           // float4/point
    size_t off_hist  = off_spts + sz_spts;
    size_t off_offs  = off_hist + (size_t)NBINS * sizeof(unsigned);
    size_t need_sort = off_offs + (size_t)NBINS * sizeof(unsigned);

    int nptblk = (npts + 255) / 256;

    if (ws_size >= need_sort) {
        float*    tp   = (float*)d_ws;
        float*    sp4  = (float*)((char*)d_ws + off_spts);
        unsigned* hist = (unsigned*)((char*)d_ws + off_hist);
        unsigned* offs = (unsigned*)((char*)d_ws + off_offs);

        hipMemsetAsync(hist, 0, (size_t)NBINS * sizeof(unsigned), stream);
        transpose_hist<<<TRBLK + nptblk, 256, 0, stream>>>(
            planes, tp, pts, hist, npts);
        scan_kernel<<<1, 1024, 0, stream>>>(hist, offs);
        scatter_kernel<<<nptblk, 256, 0, stream>>>(pts, offs, sp4, npts);

        long nthr = (long)npts * 16;
        int  nblk = (int)((nthr + 255) / 256);
        nblk = (nblk + 7) & ~7;                 // multiple of 8 for bijective swizzle
        gather_sorted<<<nblk, 256, 0, stream>>>(sp4, tp, out, npts, nblk);
    } else if (ws_size >= sz_tp) {
        transpose_hist<<<TRBLK, 256, 0, stream>>>(
            planes, (float*)d_ws, nullptr, nullptr, 0);
        long nthr = (long)npts * 16;
        gather_tp<<<(int)((nthr + 255) / 256), 256, 0, stream>>>(
            pts, (const float*)d_ws, out, npts);
    } else {
        long nthr = (long)npts * 64;
        gather_direct<<<(int)((nthr + 255) / 256), 256, 0, stream>>>(
            pts, planes, out, npts);
    }
}